// Round 9
// baseline (238.690 us; speedup 1.0000x reference)
//
#include <hip/hip_runtime.h>

typedef __attribute__((ext_vector_type(8))) short bf16x8;
typedef __attribute__((ext_vector_type(4))) float f32x4;

#define MFMA16(a,b,c) __builtin_amdgcn_mfma_f32_16x16x32_bf16((a),(b),(c),0,0,0)

__device__ __forceinline__ float b2f(unsigned short u){
  union { unsigned u; float f; } x; x.u = ((unsigned)u) << 16; return x.f;
}
__device__ __forceinline__ unsigned short f2b(float f){
  union { float f; unsigned u; } x; x.f = f;
  unsigned r = x.u + 0x7FFFu + ((x.u >> 16) & 1u);
  return (unsigned short)(r >> 16);
}
__device__ __forceinline__ unsigned pk_rne(float a, float b){
  unsigned ua = __float_as_uint(a), ub = __float_as_uint(b);
  ua += 0x7FFFu + ((ua >> 16) & 1u);
  ub += 0x7FFFu + ((ub >> 16) & 1u);
  return __builtin_amdgcn_perm(ub, ua, 0x07060302u);
}
__device__ __forceinline__ unsigned pk_trunc(float a, float b){
  return __builtin_amdgcn_perm(__float_as_uint(b), __float_as_uint(a), 0x07060302u);
}
__device__ __forceinline__ bf16x8 mk8(unsigned a, unsigned b, unsigned c, unsigned d){
  union { uint4 u; bf16x8 h; } x; x.u = make_uint4(a,b,c,d); return x.h;
}
// cluster-index bit rotation so register Sᵀ fragments align with PV's B-operand k-slots
__device__ __forceinline__ int permp(int cl){
  return (cl & 0xE0) | (((cl >> 2) & 3) << 3) | (((cl >> 4) & 1) << 2) | (cl & 3);
}

typedef __attribute__((address_space(3))) unsigned int lds_u32;
typedef const __attribute__((address_space(1))) unsigned int glb_u32;
__device__ __forceinline__ void gl_lds16(const void* g, void* l){
  __builtin_amdgcn_global_load_lds((glb_u32*)g, (lds_u32*)l, 16, 0, 0);
}

// ---------------- prep: posmax (blocks 0..63) + cvt qkv_w (64..279) + cvt proj_w (280..351) ----------------
__global__ __launch_bounds__(256) void prep_kernel(
    const float* __restrict__ pos, unsigned* __restrict__ pmax,
    const float* __restrict__ qkv_w, unsigned short* __restrict__ qkvwb,
    const float* __restrict__ proj_w, unsigned short* __restrict__ projwb)
{
  int bid = blockIdx.x, tid = threadIdx.x;
  if (bid < 64){
    int i = bid*256 + tid;
    float4 v = ((const float4*)pos)[i];
    float m0 = fmaxf(v.x, v.z), m1 = fmaxf(v.y, v.w);
    #pragma unroll
    for (int off = 32; off >= 1; off >>= 1){
      m0 = fmaxf(m0, __shfl_xor(m0, off, 64));
      m1 = fmaxf(m1, __shfl_xor(m1, off, 64));
    }
    if ((tid & 63) == 0){
      atomicMax(&pmax[0], __float_as_uint(m0));
      atomicMax(&pmax[1], __float_as_uint(m1));
    }
  } else {
    const float* in; unsigned short* o; long i;
    if (bid < 280){ in = qkv_w;  o = qkvwb;  i = (long)(bid-64)*256 + tid; }
    else          { in = proj_w; o = projwb; i = (long)(bid-280)*256 + tid; }
    const float4* p = (const float4*)(in + i*8);
    float4 a = p[0], b = p[1];
    *(uint4*)(o + i*8) = make_uint4(pk_rne(a.x,a.y), pk_rne(a.z,a.w),
                                    pk_rne(b.x,b.y), pk_rne(b.z,b.w));
  }
}

// ---------------- per-cluster feat & pos means: 2 clusters/block, float4 loads ----------------
__global__ __launch_bounds__(192) void cluster_means_kernel(
    const float* __restrict__ feat, const float* __restrict__ pos,
    const int* __restrict__ member_idx, const int* __restrict__ batch_idx,
    unsigned short* __restrict__ fm, float* __restrict__ pm)
{
  int t = threadIdx.x;
  int g = t / 96, tl = t - g*96;
  int z = blockIdx.x*2 + g;
  __shared__ int bases[2][32];
  if (tl < 32) bases[g][tl] = batch_idx[z*32 + tl]*8192 + member_idx[z*32 + tl];
  __syncthreads();
  float4 a = {0.f,0.f,0.f,0.f};
  float p = 0.f;
  const float4* f4 = (const float4*)feat;
  #pragma unroll 8
  for (int m = 0; m < 32; m++){
    int row = bases[g][m];
    float4 v = f4[(long)row*96 + tl];
    a.x += v.x; a.y += v.y; a.z += v.z; a.w += v.w;
    if (tl < 2) p += pos[(long)row*2 + tl];
  }
  unsigned d0 = pk_rne(a.x*(1.f/32.f), a.y*(1.f/32.f));
  unsigned d1 = pk_rne(a.z*(1.f/32.f), a.w*(1.f/32.f));
  *(uint2*)(fm + (long)z*384 + tl*4) = make_uint2(d0, d1);
  if (tl < 2) pm[z*2 + tl] = p * (1.f/32.f);
}

// ---------------- wt[b,h,p(cl)] = bf16(e^bias) ----------------
__global__ __launch_bounds__(256) void bias_kernel(
    const float* __restrict__ pm, const float* __restrict__ pmaxf,
    const float* __restrict__ pos_w, const float* __restrict__ pos_b,
    unsigned short* __restrict__ wt)
{
  int idx = blockIdx.x*256 + threadIdx.x;
  int kc = idx & 255;
  int bh = idx >> 8;
  int h = bh % 12;
  float p0 = pm[((bh/12)*256 + kc)*2]   / pmaxf[0];
  float p1 = pm[((bh/12)*256 + kc)*2+1] / pmaxf[1];
  float bias = p0*pos_w[h*2] + p1*pos_w[h*2+1] + pos_b[h];
  wt[(bh << 8) + permp(kc)] = f2b(exp2f(bias * 1.44269504088896340f));
}

// ---------------- kv GEMM (M=1024,N=768,K=384), 64x128 tile ----------------
__global__ __launch_bounds__(256) void gemm_kv_kernel(
    const unsigned short* __restrict__ A, const unsigned short* __restrict__ W,
    const float* __restrict__ bias, unsigned short* __restrict__ kh,
    unsigned short* __restrict__ vt, const unsigned short* __restrict__ wt)
{
  __shared__ unsigned short As[64*64];
  __shared__ unsigned short Ws[128*64];
  const int N = 768, K = 384;
  int mt = blockIdx.x / 6, nt = blockIdx.x - mt*6;
  int m0 = mt << 6, n0 = nt << 7;
  int tid = threadIdx.x;
  int lane = tid & 63, wave = tid >> 6;
  int wr = (wave >> 1) << 5, wc = (wave & 1) << 6;
  int l15 = lane & 15, quad = lane >> 4;
  int sw = l15 & 7;
  int srow = tid >> 3, sc8 = tid & 7;

  f32x4 acc[2][4];
  #pragma unroll
  for (int i = 0; i < 2; i++)
    #pragma unroll
    for (int j = 0; j < 4; j++) acc[i][j] = (f32x4){0.f,0.f,0.f,0.f};

  for (int k0 = 0; k0 < K; k0 += 64){
    __syncthreads();
    #pragma unroll
    for (int it = 0; it < 2; it++){
      int r = srow + it*32;
      int gc8 = sc8 ^ (r & 7);
      gl_lds16(A + (long)(m0+r)*K + k0 + gc8*8, As + it*2048 + wave*512);
    }
    #pragma unroll
    for (int it = 0; it < 4; it++){
      int r = srow + it*32;
      int gc8 = sc8 ^ (r & 7);
      gl_lds16(W + (long)(n0+r)*K + k0 + gc8*8, Ws + it*2048 + wave*512);
    }
    __syncthreads();
    #pragma unroll
    for (int kk = 0; kk < 2; kk++){
      bf16x8 af[2], bfr[4];
      #pragma unroll
      for (int i = 0; i < 2; i++)
        af[i] = *(const bf16x8*)(As + (wr + i*16 + l15)*64 + (((kk<<2)+quad) ^ sw)*8);
      #pragma unroll
      for (int j = 0; j < 4; j++)
        bfr[j] = *(const bf16x8*)(Ws + (wc + j*16 + l15)*64 + (((kk<<2)+quad) ^ sw)*8);
      #pragma unroll
      for (int i = 0; i < 2; i++)
        #pragma unroll
        for (int j = 0; j < 4; j++)
          acc[i][j] = MFMA16(af[i], bfr[j], acc[i][j]);
    }
  }

  #pragma unroll
  for (int j = 0; j < 4; j++){
    int col = n0 + wc + j*16 + l15;
    float bv = bias[col];
    #pragma unroll
    for (int i = 0; i < 2; i++){
      int row0 = m0 + wr + i*16 + quad*4;
      #pragma unroll
      for (int r = 0; r < 4; r++){
        float v = acc[i][j][r] + bv;
        int row = row0 + r;
        int b = row >> 8, cl = row & 255;
        if (col < 384){
          int h = col >> 5, ch = col & 31;
          kh[((((long)b*12 + h)*256 + cl)*32) + ch] = f2b(v);
        } else {
          int cn = col - 384;
          int h = cn >> 5, ch = cn & 31;
          int pp = permp(cl);
          int c8 = (pp >> 3) ^ (ch & 7);
          float w = b2f(wt[(((long)b*12 + h) << 8) + pp]);
          vt[(((long)b*12 + h)*32 + ch)*256 + c8*8 + (pp & 7)] = f2b(v * w);
        }
      }
    }
  }
}

// ---------------- full-N GEMM v2: A-resident-in-LDS, W-streamed-from-L2 ----------------
// C[M,384] = (A[M,384] @ W[384,384]^T + bias) * out_scale
// Block: 64 M-rows, full K in LDS (48 KB), staged ONCE -> single barrier.
// 512 thr / 8 waves; wave w owns n-cols [w*48, w*48+48). K-loop: no barriers,
// A-frags from LDS, W-frags streamed global->reg (L2-resident, shared by all blocks).
template<int OUT_F32, int AF32>
__global__ __launch_bounds__(512) void gemm_fn_kernel(
    const void* __restrict__ Av, const unsigned short* __restrict__ W,
    const float* __restrict__ bias, void* __restrict__ Cv, float out_scale)
{
  __shared__ unsigned short As[6*64*64];  // [it][row][c8*8] = 48 KB
  const int K = 384, N = 384;
  int m0 = blockIdx.x << 6;
  int tid = threadIdx.x;
  int lane = tid & 63, wave = tid >> 6;
  int l15 = lane & 15, quad = lane >> 4;
  int sr = tid >> 3, sc8 = tid & 7;

  // stage A (full K) once
  if (AF32){
    const float* Af = (const float*)Av;
    #pragma unroll
    for (int it = 0; it < 6; it++){
      int gc = it*64 + (sc8 ^ (sr & 7))*8;
      const float4* src = (const float4*)(Af + (long)(m0+sr)*K + gc);
      float4 v0 = src[0], v1 = src[1];
      *(uint4*)(As + it*4096 + sr*64 + sc8*8) =
        make_uint4(pk_rne(v0.x,v0.y), pk_rne(v0.z,v0.w), pk_rne(v1.x,v1.y), pk_rne(v1.z,v1.w));
    }
  } else {
    const unsigned short* A = (const unsigned short*)Av;
    #pragma unroll
    for (int it = 0; it < 6; it++){
      int gc8 = sc8 ^ (sr & 7);
      gl_lds16(A + (long)(m0+sr)*K + it*64 + gc8*8, As + it*4096 + wave*512);
    }
  }
  __syncthreads();

  f32x4 acc[4][3];
  #pragma unroll
  for (int i = 0; i < 4; i++)
    #pragma unroll
    for (int j = 0; j < 3; j++) acc[i][j] = (f32x4){0.f,0.f,0.f,0.f};

  int n0w = wave*48;
  #pragma unroll
  for (int ks = 0; ks < 12; ks++){
    int it = ks >> 1, cb = (ks & 1)*4;
    bf16x8 af[4], bw[3];
    #pragma unroll
    for (int j = 0; j < 3; j++)
      bw[j] = *(const bf16x8*)(W + (long)(n0w + j*16 + l15)*K + ks*32 + quad*8);
    #pragma unroll
    for (int i = 0; i < 4; i++){
      int r = i*16 + l15;
      af[i] = *(const bf16x8*)(As + it*4096 + r*64 + (((cb+quad) ^ (l15 & 7))*8));
    }
    #pragma unroll
    for (int i = 0; i < 4; i++)
      #pragma unroll
      for (int j = 0; j < 3; j++)
        acc[i][j] = MFMA16(af[i], bw[j], acc[i][j]);
  }

  #pragma unroll
  for (int j = 0; j < 3; j++){
    int col = n0w + j*16 + l15;
    float bv = bias[col];
    #pragma unroll
    for (int i = 0; i < 4; i++){
      int row0 = m0 + i*16 + quad*4;
      #pragma unroll
      for (int r = 0; r < 4; r++){
        float v = (acc[i][j][r] + bv) * out_scale;
        if (OUT_F32) ((float*)Cv)[(long)(row0+r)*N + col] = v;
        else ((unsigned short*)Cv)[(long)(row0+r)*N + col] = f2b(v);
      }
    }
  }
}

// ---------------- fused attention (S^T formulation, no P LDS round-trip) ----------------
// block = (b, h, 64 tokens), 256 thr / 4 waves, 16 tokens per wave; 4 blocks/CU.
__global__ __launch_bounds__(256) void attn_kernel(
    const unsigned short* __restrict__ qs,   // (B*N,384) bf16, scale*log2e folded
    const unsigned short* __restrict__ kh,   // (B,H,256,32) bf16, natural
    const unsigned short* __restrict__ vt,   // (B,H,32,256) bf16, p-permuted+swizzled, w-folded
    const unsigned short* __restrict__ wt,   // (B*H,256) bf16 w, p-permuted
    unsigned short* __restrict__ ao)         // (B*N,384) bf16
{
  __shared__ unsigned short keyS[256*32];    // 16 KB [cl][ch]
  __shared__ unsigned short vTS[32*256];     // 16 KB [ch][pos] swizzled
  __shared__ unsigned short wS[256];         // 0.5 KB [pos]

  int bid = blockIdx.x;
  int chunk = bid & 127;
  int h = (bid >> 7) % 12;
  int b = bid / (128*12);
  int bh = b*12 + h;
  int n0 = chunk << 6;
  int tid = threadIdx.x, lane = tid & 63, wave = tid >> 6;
  int l15 = lane & 15, quad = lane >> 4;
  int sw = l15 & 7;

  const unsigned short* khb = kh + (long)bh*8192;
  const unsigned short* vtb = vt + (long)bh*8192;
  #pragma unroll
  for (int it = 0; it < 4; it++){
    gl_lds16(khb + it*2048 + tid*8, keyS + it*2048 + wave*512);
    gl_lds16(vtb + it*2048 + tid*8, vTS  + it*2048 + wave*512);
  }
  if (tid < 32) *(uint4*)(wS + tid*8) = *(const uint4*)(wt + ((long)bh << 8) + tid*8);
  __syncthreads();

  int tok0 = n0 + wave*16;
  bf16x8 aq = *(const bf16x8*)(qs + ((long)b*8192 + tok0 + l15)*384 + h*32 + quad*8);

  // S^T = K @ q^T : D[cl_local = quad*4+c][tok = l15], cl = kb*16 + quad*4 + c
  f32x4 S[16];
  #pragma unroll
  for (int kb = 0; kb < 16; kb++){
    bf16x8 bk = *(const bf16x8*)(keyS + (kb*16 + l15)*32 + quad*8);
    f32x4 z = {0.f,0.f,0.f,0.f};
    S[kb] = MFMA16(bk, aq, z);
  }

  // P^T = exp2(S^T) in registers (no max shift; logits tiny)
  #pragma unroll
  for (int kb = 0; kb < 16; kb++)
    #pragma unroll
    for (int c = 0; c < 4; c++) S[kb][c] = exp2f(S[kb][c]);

  // O^T = V'^T @ P^T ; denom = w @ P^T  — P^T fragments packed from registers
  f32x4 o0 = {0.f,0.f,0.f,0.f}, o1 = {0.f,0.f,0.f,0.f}, os = {0.f,0.f,0.f,0.f};
  #pragma unroll
  for (int ks = 0; ks < 8; ks++){
    bf16x8 pf = mk8(pk_trunc(S[2*ks][0],   S[2*ks][1]),
                    pk_trunc(S[2*ks][2],   S[2*ks][3]),
                    pk_trunc(S[2*ks+1][0], S[2*ks+1][1]),
                    pk_trunc(S[2*ks+1][2], S[2*ks+1][3]));
    int c8 = (4*ks + quad) ^ sw;
    bf16x8 a0 = *(const bf16x8*)(vTS + l15*256      + c8*8);
    bf16x8 a1 = *(const bf16x8*)(vTS + (16+l15)*256 + c8*8);
    bf16x8 wf = *(const bf16x8*)(wS + ks*32 + quad*8);
    o0 = MFMA16(a0, pf, o0);
    o1 = MFMA16(a1, pf, o1);
    os = MFMA16(wf, pf, os);
  }
  float inv = 1.f / os[0];
  long obase = ((long)b*8192 + tok0 + l15)*384 + h*32 + quad*4;
  unsigned q0 = pk_rne(o0[0]*inv, o0[1]*inv), q1 = pk_rne(o0[2]*inv, o0[3]*inv);
  unsigned q2 = pk_rne(o1[0]*inv, o1[1]*inv), q3 = pk_rne(o1[2]*inv, o1[3]*inv);
  *(uint2*)(ao + obase)      = make_uint2(q0, q1);
  *(uint2*)(ao + obase + 16) = make_uint2(q2, q3);
}

extern "C" void kernel_launch(void* const* d_in, const int* in_sizes, int n_in,
                              void* d_out, int out_size, void* d_ws, size_t ws_size,
                              hipStream_t stream)
{
  const float* pos      = (const float*)d_in[0];
  const float* feat     = (const float*)d_in[1];
  const int* member_idx = (const int*)d_in[2];
  const int* batch_idx  = (const int*)d_in[3];
  const float* qkv_w    = (const float*)d_in[4];
  const float* qkv_b    = (const float*)d_in[5];
  const float* pos_w    = (const float*)d_in[6];
  const float* pos_b    = (const float*)d_in[7];
  const float* proj_w   = (const float*)d_in[8];
  const float* proj_b   = (const float*)d_in[9];
  float* out = (float*)d_out;

  char* ws = (char*)d_ws;
  float* pmax           = (float*)ws;                       // 8 B
  float* pm             = (float*)(ws + 256);               // 8 KB
  unsigned short* fm    = (unsigned short*)(ws + 8704);     // 1024x384 bf16
  unsigned short* kh    = (unsigned short*)(ws + 795136);   // 4x12x256x32 bf16
  unsigned short* vt    = (unsigned short*)(ws + 1581568);  // 4x12x32x256 bf16
  unsigned short* wt    = (unsigned short*)(ws + 2368000);  // 4x12x256 bf16
  unsigned short* q_s   = (unsigned short*)(ws + 2417152);  // 32768x384 bf16
  unsigned short* ao    = (unsigned short*)(ws + 27582976); // 32768x384 bf16
  unsigned short* qkvwb = (unsigned short*)(ws + 52748800); // 1152x384 bf16
  unsigned short* projwb= (unsigned short*)(ws + 53633536); // 384x384 bf16

  hipMemsetAsync(pmax, 0, 8, stream);
  prep_kernel<<<352, 256, 0, stream>>>(pos, (unsigned*)pmax, qkv_w, qkvwb, proj_w, projwb);
  cluster_means_kernel<<<512, 192, 0, stream>>>(feat, pos, member_idx, batch_idx, fm, pm);
  bias_kernel<<<48, 256, 0, stream>>>(pm, pmax, pos_w, pos_b, wt);
  gemm_kv_kernel<<<96, 256, 0, stream>>>(fm, qkvwb + 384*384, qkv_b + 384, kh, vt, wt);
  // q = feat(f32) @ Wq^T + bq, scale*log2e folded
  gemm_fn_kernel<0,1><<<512, 512, 0, stream>>>(feat, qkvwb, qkv_b, q_s,
                                               0.17677669529663687f * 1.44269504088896340f);
  attn_kernel<<<6144, 256, 0, stream>>>(q_s, kh, vt, wt, ao);
  gemm_fn_kernel<1,0><<<512, 512, 0, stream>>>(ao, projwb, proj_b, out, 1.0f);
}

// Round 10
// 217.880 us; speedup vs baseline: 1.0955x; 1.0955x over previous
//
#include <hip/hip_runtime.h>

typedef __attribute__((ext_vector_type(8))) short bf16x8;
typedef __attribute__((ext_vector_type(4))) float f32x4;

#define MFMA16(a,b,c) __builtin_amdgcn_mfma_f32_16x16x32_bf16((a),(b),(c),0,0,0)

__device__ __forceinline__ float b2f(unsigned short u){
  union { unsigned u; float f; } x; x.u = ((unsigned)u) << 16; return x.f;
}
__device__ __forceinline__ unsigned short f2b(float f){
  union { float f; unsigned u; } x; x.f = f;
  unsigned r = x.u + 0x7FFFu + ((x.u >> 16) & 1u);
  return (unsigned short)(r >> 16);
}
__device__ __forceinline__ unsigned pk_rne(float a, float b){
  unsigned ua = __float_as_uint(a), ub = __float_as_uint(b);
  ua += 0x7FFFu + ((ua >> 16) & 1u);
  ub += 0x7FFFu + ((ub >> 16) & 1u);
  return __builtin_amdgcn_perm(ub, ua, 0x07060302u);
}
__device__ __forceinline__ unsigned pk_trunc(float a, float b){
  return __builtin_amdgcn_perm(__float_as_uint(b), __float_as_uint(a), 0x07060302u);
}
__device__ __forceinline__ bf16x8 mk8(unsigned a, unsigned b, unsigned c, unsigned d){
  union { uint4 u; bf16x8 h; } x; x.u = make_uint4(a,b,c,d); return x.h;
}
// cluster-index bit rotation so register Sᵀ fragments align with PV's B-operand k-slots
__device__ __forceinline__ int permp(int cl){
  return (cl & 0xE0) | (((cl >> 2) & 3) << 3) | (((cl >> 4) & 1) << 2) | (cl & 3);
}

typedef __attribute__((address_space(3))) unsigned int lds_u32;
typedef const __attribute__((address_space(1))) unsigned int glb_u32;
__device__ __forceinline__ void gl_lds16(const void* g, void* l){
  __builtin_amdgcn_global_load_lds((glb_u32*)g, (lds_u32*)l, 16, 0, 0);
}

// ---------------- prep: posmax (blocks 0..63) + cvt qkv_w (64..279) + cvt proj_w (280..351) ----------------
__global__ __launch_bounds__(256) void prep_kernel(
    const float* __restrict__ pos, unsigned* __restrict__ pmax,
    const float* __restrict__ qkv_w, unsigned short* __restrict__ qkvwb,
    const float* __restrict__ proj_w, unsigned short* __restrict__ projwb)
{
  int bid = blockIdx.x, tid = threadIdx.x;
  if (bid < 64){
    int i = bid*256 + tid;
    float4 v = ((const float4*)pos)[i];
    float m0 = fmaxf(v.x, v.z), m1 = fmaxf(v.y, v.w);
    #pragma unroll
    for (int off = 32; off >= 1; off >>= 1){
      m0 = fmaxf(m0, __shfl_xor(m0, off, 64));
      m1 = fmaxf(m1, __shfl_xor(m1, off, 64));
    }
    if ((tid & 63) == 0){
      atomicMax(&pmax[0], __float_as_uint(m0));
      atomicMax(&pmax[1], __float_as_uint(m1));
    }
  } else {
    const float* in; unsigned short* o; long i;
    if (bid < 280){ in = qkv_w;  o = qkvwb;  i = (long)(bid-64)*256 + tid; }
    else          { in = proj_w; o = projwb; i = (long)(bid-280)*256 + tid; }
    const float4* p = (const float4*)(in + i*8);
    float4 a = p[0], b = p[1];
    *(uint4*)(o + i*8) = make_uint4(pk_rne(a.x,a.y), pk_rne(a.z,a.w),
                                    pk_rne(b.x,b.y), pk_rne(b.z,b.w));
  }
}

// ---------------- per-cluster feat & pos means: 2 clusters/block, float4 loads ----------------
__global__ __launch_bounds__(192) void cluster_means_kernel(
    const float* __restrict__ feat, const float* __restrict__ pos,
    const int* __restrict__ member_idx, const int* __restrict__ batch_idx,
    unsigned short* __restrict__ fm, float* __restrict__ pm)
{
  int t = threadIdx.x;
  int g = t / 96, tl = t - g*96;
  int z = blockIdx.x*2 + g;
  __shared__ int bases[2][32];
  if (tl < 32) bases[g][tl] = batch_idx[z*32 + tl]*8192 + member_idx[z*32 + tl];
  __syncthreads();
  float4 a = {0.f,0.f,0.f,0.f};
  float p = 0.f;
  const float4* f4 = (const float4*)feat;
  #pragma unroll 8
  for (int m = 0; m < 32; m++){
    int row = bases[g][m];
    float4 v = f4[(long)row*96 + tl];
    a.x += v.x; a.y += v.y; a.z += v.z; a.w += v.w;
    if (tl < 2) p += pos[(long)row*2 + tl];
  }
  unsigned d0 = pk_rne(a.x*(1.f/32.f), a.y*(1.f/32.f));
  unsigned d1 = pk_rne(a.z*(1.f/32.f), a.w*(1.f/32.f));
  *(uint2*)(fm + (long)z*384 + tl*4) = make_uint2(d0, d1);
  if (tl < 2) pm[z*2 + tl] = p * (1.f/32.f);
}

// ---------------- wt[b,h,p(cl)] = bf16(e^bias) ----------------
__global__ __launch_bounds__(256) void bias_kernel(
    const float* __restrict__ pm, const float* __restrict__ pmaxf,
    const float* __restrict__ pos_w, const float* __restrict__ pos_b,
    unsigned short* __restrict__ wt)
{
  int idx = blockIdx.x*256 + threadIdx.x;
  int kc = idx & 255;
  int bh = idx >> 8;
  int h = bh % 12;
  float p0 = pm[((bh/12)*256 + kc)*2]   / pmaxf[0];
  float p1 = pm[((bh/12)*256 + kc)*2+1] / pmaxf[1];
  float bias = p0*pos_w[h*2] + p1*pos_w[h*2+1] + pos_b[h];
  wt[(bh << 8) + permp(kc)] = f2b(exp2f(bias * 1.44269504088896340f));
}

// ---------------- kv GEMM (M=1024,N=768,K=384), 64x128 tile ----------------
__global__ __launch_bounds__(256) void gemm_kv_kernel(
    const unsigned short* __restrict__ A, const unsigned short* __restrict__ W,
    const float* __restrict__ bias, unsigned short* __restrict__ kh,
    unsigned short* __restrict__ vt, const unsigned short* __restrict__ wt)
{
  __shared__ unsigned short As[64*64];
  __shared__ unsigned short Ws[128*64];
  const int N = 768, K = 384;
  int mt = blockIdx.x / 6, nt = blockIdx.x - mt*6;
  int m0 = mt << 6, n0 = nt << 7;
  int tid = threadIdx.x;
  int lane = tid & 63, wave = tid >> 6;
  int wr = (wave >> 1) << 5, wc = (wave & 1) << 6;
  int l15 = lane & 15, quad = lane >> 4;
  int sw = l15 & 7;
  int srow = tid >> 3, sc8 = tid & 7;

  f32x4 acc[2][4];
  #pragma unroll
  for (int i = 0; i < 2; i++)
    #pragma unroll
    for (int j = 0; j < 4; j++) acc[i][j] = (f32x4){0.f,0.f,0.f,0.f};

  for (int k0 = 0; k0 < K; k0 += 64){
    __syncthreads();
    #pragma unroll
    for (int it = 0; it < 2; it++){
      int r = srow + it*32;
      int gc8 = sc8 ^ (r & 7);
      gl_lds16(A + (long)(m0+r)*K + k0 + gc8*8, As + it*2048 + wave*512);
    }
    #pragma unroll
    for (int it = 0; it < 4; it++){
      int r = srow + it*32;
      int gc8 = sc8 ^ (r & 7);
      gl_lds16(W + (long)(n0+r)*K + k0 + gc8*8, Ws + it*2048 + wave*512);
    }
    __syncthreads();
    #pragma unroll
    for (int kk = 0; kk < 2; kk++){
      bf16x8 af[2], bfr[4];
      #pragma unroll
      for (int i = 0; i < 2; i++)
        af[i] = *(const bf16x8*)(As + (wr + i*16 + l15)*64 + (((kk<<2)+quad) ^ sw)*8);
      #pragma unroll
      for (int j = 0; j < 4; j++)
        bfr[j] = *(const bf16x8*)(Ws + (wc + j*16 + l15)*64 + (((kk<<2)+quad) ^ sw)*8);
      #pragma unroll
      for (int i = 0; i < 2; i++)
        #pragma unroll
        for (int j = 0; j < 4; j++)
          acc[i][j] = MFMA16(af[i], bfr[j], acc[i][j]);
    }
  }

  #pragma unroll
  for (int j = 0; j < 4; j++){
    int col = n0 + wc + j*16 + l15;
    float bv = bias[col];
    #pragma unroll
    for (int i = 0; i < 2; i++){
      int row0 = m0 + wr + i*16 + quad*4;
      #pragma unroll
      for (int r = 0; r < 4; r++){
        float v = acc[i][j][r] + bv;
        int row = row0 + r;
        int b = row >> 8, cl = row & 255;
        if (col < 384){
          int h = col >> 5, ch = col & 31;
          kh[((((long)b*12 + h)*256 + cl)*32) + ch] = f2b(v);
        } else {
          int cn = col - 384;
          int h = cn >> 5, ch = cn & 31;
          int pp = permp(cl);
          int c8 = (pp >> 3) ^ (ch & 7);
          float w = b2f(wt[(((long)b*12 + h) << 8) + pp]);
          vt[(((long)b*12 + h)*32 + ch)*256 + c8*8 + (pp & 7)] = f2b(v * w);
        }
      }
    }
  }
}

// ---------------- full-N GEMM (round-8 structure): 64x384 tile, BK=64, 512 thr / 8 waves ----------------
// AF32: A is f32 (token-major), register-cvt staging. AHM: A is bf16 HEAD-MAJOR [bh][tok][32].
// CHM: write C bf16 head-major. OUT_F32: write C f32 token-major.
template<int OUT_F32, int AF32, int AHM, int CHM>
__global__ __launch_bounds__(512) void gemm_fn_kernel(
    const void* __restrict__ Av, const unsigned short* __restrict__ W,
    const float* __restrict__ bias, void* __restrict__ Cv, float out_scale)
{
  __shared__ unsigned short As[64*72];    // AF32: stride 72 (padded); bf16: stride 64
  __shared__ unsigned short Ws[384*64];   // 48 KB
  const int K = 384, N = 384;
  int m0 = blockIdx.x << 6;
  int tid = threadIdx.x;
  int lane = tid & 63, wave = tid >> 6;
  int l15 = lane & 15, quad = lane >> 4;
  int sw = l15 & 7;
  int srow = tid >> 3, sc8 = tid & 7;     // 512 thr: srow 0..63

  f32x4 acc[4][3];
  #pragma unroll
  for (int i = 0; i < 4; i++)
    #pragma unroll
    for (int j = 0; j < 3; j++) acc[i][j] = (f32x4){0.f,0.f,0.f,0.f};

  for (int k0 = 0; k0 < K; k0 += 64){
    __syncthreads();
    if (AF32){
      const float* Af = (const float*)Av;
      const float4* src = (const float4*)(Af + (long)(m0+srow)*K + k0 + sc8*8);
      float4 v0 = src[0], v1 = src[1];
      *(uint4*)(As + srow*72 + sc8*8) = make_uint4(pk_rne(v0.x,v0.y), pk_rne(v0.z,v0.w),
                                                   pk_rne(v1.x,v1.y), pk_rne(v1.z,v1.w));
    } else {
      const unsigned short* A = (const unsigned short*)Av;
      int gc8 = sc8 ^ (srow & 7);
      const unsigned short* src;
      if (AHM){
        int row = m0 + srow;
        int bb = row >> 13, tok = row & 8191;
        int ch = k0 + gc8*8;
        src = A + ((((long)(bb*12 + (ch >> 5))) << 13) + tok)*32 + (ch & 31);
      } else {
        src = A + (long)(m0+srow)*K + k0 + gc8*8;
      }
      gl_lds16(src, As + wave*512);
    }
    #pragma unroll
    for (int it = 0; it < 6; it++){
      int r = it*64 + srow;
      int gc8 = sc8 ^ (r & 7);
      gl_lds16(W + (long)r*K + k0 + gc8*8, Ws + it*4096 + wave*512);
    }
    __syncthreads();
    #pragma unroll
    for (int kk = 0; kk < 2; kk++){
      bf16x8 af[4];
      #pragma unroll
      for (int i = 0; i < 4; i++){
        int r = i*16 + l15;
        if (AF32) af[i] = *(const bf16x8*)(As + r*72 + ((kk<<2)+quad)*8);
        else      af[i] = *(const bf16x8*)(As + r*64 + (((kk<<2)+quad) ^ sw)*8);
      }
      #pragma unroll
      for (int j = 0; j < 3; j++){
        bf16x8 bfr = *(const bf16x8*)(Ws + (wave*48 + j*16 + l15)*64 + (((kk<<2)+quad) ^ sw)*8);
        #pragma unroll
        for (int i = 0; i < 4; i++)
          acc[i][j] = MFMA16(af[i], bfr, acc[i][j]);
      }
    }
  }

  #pragma unroll
  for (int j = 0; j < 3; j++){
    int col = wave*48 + j*16 + l15;
    float bv = bias[col];
    #pragma unroll
    for (int i = 0; i < 4; i++){
      int row0 = m0 + i*16 + quad*4;
      #pragma unroll
      for (int r = 0; r < 4; r++){
        float v = (acc[i][j][r] + bv) * out_scale;
        int row = row0 + r;
        if (OUT_F32){
          ((float*)Cv)[(long)row*N + col] = v;
        } else if (CHM){
          int bb = row >> 13, tok = row & 8191;
          ((unsigned short*)Cv)[((((long)(bb*12 + (col >> 5))) << 13) + tok)*32 + (col & 31)] = f2b(v);
        } else {
          ((unsigned short*)Cv)[(long)row*N + col] = f2b(v);
        }
      }
    }
  }
}

// ---------------- fused attention (S^T, head-major I/O, 2 token-tiles per wave) ----------------
// block = (b, h, 128 tokens), 256 thr / 4 waves; wave handles 2 tiles of 16 tokens.
__global__ __launch_bounds__(256) void attn_kernel(
    const unsigned short* __restrict__ qhm,  // (B*H,8192,32) bf16 head-major, scale*log2e folded
    const unsigned short* __restrict__ kh,   // (B,H,256,32) bf16, natural
    const unsigned short* __restrict__ vt,   // (B,H,32,256) bf16, p-permuted+swizzled, w-folded
    const unsigned short* __restrict__ wt,   // (B*H,256) bf16 w, p-permuted
    unsigned short* __restrict__ aohm)       // (B*H,8192,32) bf16 head-major
{
  __shared__ unsigned short keyS[256*32];    // 16 KB [cl][ch]
  __shared__ unsigned short vTS[32*256];     // 16 KB [ch][pos] swizzled
  __shared__ unsigned short wS[256];         // 0.5 KB [pos]

  int bid = blockIdx.x;
  int chunk = bid & 63;                      // 8192/128
  int bh = bid >> 6;                         // b*12 + h
  int n0 = chunk << 7;
  int tid = threadIdx.x, lane = tid & 63, wave = tid >> 6;
  int l15 = lane & 15, quad = lane >> 4;
  int sw = l15 & 7;

  const unsigned short* khb = kh + (long)bh*8192;
  const unsigned short* vtb = vt + (long)bh*8192;
  #pragma unroll
  for (int it = 0; it < 4; it++){
    gl_lds16(khb + it*2048 + tid*8, keyS + it*2048 + wave*512);
    gl_lds16(vtb + it*2048 + tid*8, vTS  + it*2048 + wave*512);
  }
  if (tid < 32) *(uint4*)(wS + tid*8) = *(const uint4*)(wt + ((long)bh << 8) + tid*8);

  // coalesced head-major q loads for both tiles (1 KB contiguous per wave per tile)
  long qbase = ((long)bh*8192 + n0 + wave*32 + l15)*32 + quad*8;
  bf16x8 aq0 = *(const bf16x8*)(qhm + qbase);
  bf16x8 aq1 = *(const bf16x8*)(qhm + qbase + 512);   // +16 tokens
  __syncthreads();

  #pragma unroll
  for (int ti = 0; ti < 2; ti++){
    bf16x8 aq = ti ? aq1 : aq0;

    // S^T = K @ q^T : D[cl_local = quad*4+c][tok = l15]
    f32x4 S[16];
    #pragma unroll
    for (int kb = 0; kb < 16; kb++){
      bf16x8 bk = *(const bf16x8*)(keyS + (kb*16 + l15)*32 + quad*8);
      f32x4 z = {0.f,0.f,0.f,0.f};
      S[kb] = MFMA16(bk, aq, z);
    }

    // P^T = exp2(S^T) in registers (no max shift; logits tiny)
    #pragma unroll
    for (int kb = 0; kb < 16; kb++)
      #pragma unroll
      for (int c = 0; c < 4; c++) S[kb][c] = exp2f(S[kb][c]);

    // O^T = V'^T @ P^T ; denom = w @ P^T
    f32x4 o0 = {0.f,0.f,0.f,0.f}, o1 = {0.f,0.f,0.f,0.f}, os = {0.f,0.f,0.f,0.f};
    #pragma unroll
    for (int ks = 0; ks < 8; ks++){
      bf16x8 pf = mk8(pk_trunc(S[2*ks][0],   S[2*ks][1]),
                      pk_trunc(S[2*ks][2],   S[2*ks][3]),
                      pk_trunc(S[2*ks+1][0], S[2*ks+1][1]),
                      pk_trunc(S[2*ks+1][2], S[2*ks+1][3]));
      int c8 = (4*ks + quad) ^ sw;
      bf16x8 a0 = *(const bf16x8*)(vTS + l15*256      + c8*8);
      bf16x8 a1 = *(const bf16x8*)(vTS + (16+l15)*256 + c8*8);
      bf16x8 wf = *(const bf16x8*)(wS + ks*32 + quad*8);
      o0 = MFMA16(a0, pf, o0);
      o1 = MFMA16(a1, pf, o1);
      os = MFMA16(wf, pf, os);
    }
    float inv = 1.f / os[0];
    // head-major output: wave writes 16 tok x 64 B contiguous
    long obase = ((long)bh*8192 + n0 + wave*32 + ti*16 + l15)*32 + quad*4;
    unsigned q0 = pk_rne(o0[0]*inv, o0[1]*inv), q1 = pk_rne(o0[2]*inv, o0[3]*inv);
    unsigned q2 = pk_rne(o1[0]*inv, o1[1]*inv), q3 = pk_rne(o1[2]*inv, o1[3]*inv);
    *(uint2*)(aohm + obase)      = make_uint2(q0, q1);
    *(uint2*)(aohm + obase + 16) = make_uint2(q2, q3);
  }
}

extern "C" void kernel_launch(void* const* d_in, const int* in_sizes, int n_in,
                              void* d_out, int out_size, void* d_ws, size_t ws_size,
                              hipStream_t stream)
{
  const float* pos      = (const float*)d_in[0];
  const float* feat     = (const float*)d_in[1];
  const int* member_idx = (const int*)d_in[2];
  const int* batch_idx  = (const int*)d_in[3];
  const float* qkv_w    = (const float*)d_in[4];
  const float* qkv_b    = (const float*)d_in[5];
  const float* pos_w    = (const float*)d_in[6];
  const float* pos_b    = (const float*)d_in[7];
  const float* proj_w   = (const float*)d_in[8];
  const float* proj_b   = (const float*)d_in[9];
  float* out = (float*)d_out;

  char* ws = (char*)d_ws;
  float* pmax           = (float*)ws;                       // 8 B
  float* pm             = (float*)(ws + 256);               // 8 KB
  unsigned short* fm    = (unsigned short*)(ws + 8704);     // 1024x384 bf16
  unsigned short* kh    = (unsigned short*)(ws + 795136);   // 4x12x256x32 bf16
  unsigned short* vt    = (unsigned short*)(ws + 1581568);  // 4x12x32x256 bf16
  unsigned short* wt    = (unsigned short*)(ws + 2368000);  // 4x12x256 bf16
  unsigned short* q_s   = (unsigned short*)(ws + 2417152);  // 48x8192x32 bf16 (head-major)
  unsigned short* ao    = (unsigned short*)(ws + 27582976); // 48x8192x32 bf16 (head-major)
  unsigned short* qkvwb = (unsigned short*)(ws + 52748800); // 1152x384 bf16
  unsigned short* projwb= (unsigned short*)(ws + 53633536); // 384x384 bf16

  hipMemsetAsync(pmax, 0, 8, stream);
  prep_kernel<<<352, 256, 0, stream>>>(pos, (unsigned*)pmax, qkv_w, qkvwb, proj_w, projwb);
  cluster_means_kernel<<<512, 192, 0, stream>>>(feat, pos, member_idx, batch_idx, fm, pm);
  bias_kernel<<<48, 256, 0, stream>>>(pm, pmax, pos_w, pos_b, wt);
  gemm_kv_kernel<<<96, 256, 0, stream>>>(fm, qkvwb + 384*384, qkv_b + 384, kh, vt, wt);
  // q = feat(f32) @ Wq^T + bq -> head-major q_s, scale*log2e folded
  gemm_fn_kernel<0,1,0,1><<<512, 512, 0, stream>>>(feat, qkvwb, qkv_b, q_s,
                                                   0.17677669529663687f * 1.44269504088896340f);
  attn_kernel<<<3072, 256, 0, stream>>>(q_s, kh, vt, wt, ao);
  // proj: A = head-major ao, output f32 token-major
  gemm_fn_kernel<1,0,1,0><<<512, 512, 0, stream>>>(ao, projwb, proj_b, out, 1.0f);
}